// Round 13
// baseline (91.399 us; speedup 1.0000x reference)
//
#include <hip/hip_runtime.h>
#include <hip/hip_bf16.h>

// GAT edge-average forward, factored + CSR via atomic-free bucketed counting sort:
//   A = x @ Wf[:, :64]^T            [N,64]  bf16 in ws
//   B = x @ Wf[:, 64:]^T + bf       [N,64]  f32 in ws
//   c = x @ Ww[0, :64]              [N]
//   d = x @ Ww[0, 64:] + bw         [N]
//   CSR build (no global atomics in the hot paths):
//     hist:   counts[bucket][blk] via LDS histogram (bucket = tgt>>8, NB=196)
//     scan:   scan1 (per-block) + bsum scan folded into scan1's LAST block
//             (device ticket + threadfence; no spin)
//     part:   packed (src<<8 | tgt&255) scattered to bucket regions (in d_out)
//     bsort:  per-bucket LDS counting sort, 512 threads -> starts[], sorted_src[]
//   gather: wave=node, lane=dim, unroll x8: acc += relu(A[s]+B[t])*(c[s]+d[t])

#define NBLK 512   // edge-chunk blocks for hist/partition

__global__ __launch_bounds__(256) void gat_pre_hist(
    const float* __restrict__ x, const float* __restrict__ Wf,
    const float* __restrict__ Ww, const float* __restrict__ bf,
    const float* __restrict__ bw,
    __hip_bfloat16* __restrict__ A16, float* __restrict__ B,
    float* __restrict__ cg, float* __restrict__ dg, int N,
    const int* __restrict__ tgt, int* __restrict__ counts,
    int* __restrict__ ticket, int E, int NB, int chunk, int nb1)
{
    __shared__ float w2[64][132];
    __shared__ float xs[64][68];
    __shared__ float ww[128];
    __shared__ float bfs[64];
    __shared__ int   h[256];

    const int tid = threadIdx.x;

    if (blockIdx.x == 0 && tid == 0) *ticket = 0;   // reset for scan1's last-block fold

    if (blockIdx.x >= nb1) {
        // LDS-histogram of tgt buckets for this edge chunk; plain global writes
        const int k = blockIdx.x - nb1;          // 0..NBLK-1
        h[tid] = 0;
        __syncthreads();
        const int lo = k * chunk;                // chunk % 4 == 0 -> 16B aligned
        const int hi = min(lo + chunk, E);
        const int m4 = (hi - lo) & ~3;
        for (int e = lo + tid * 4; e < lo + m4; e += 256 * 4) {
            const int4 t4 = *(const int4*)&tgt[e];
            atomicAdd(&h[t4.x >> 8], 1);
            atomicAdd(&h[t4.y >> 8], 1);
            atomicAdd(&h[t4.z >> 8], 1);
            atomicAdd(&h[t4.w >> 8], 1);
        }
        for (int e = lo + m4 + tid; e < hi; e += 256)
            atomicAdd(&h[tgt[e] >> 8], 1);       // LDS atomic (tail)
        __syncthreads();
        if (tid < NB) counts[tid * NBLK + k] = h[tid];
        return;
    }

    for (int f = tid; f < 64 * 128; f += 256) {
        int d  = f >> 7;
        int kk = f & 127;
        w2[kk & 63][(kk >> 6) * 64 + d] = Wf[f];
    }
    if (tid < 128) ww[tid] = Ww[tid];
    if (tid < 64)  bfs[tid] = bf[tid];

    const int n0 = blockIdx.x << 6;
    for (int i = tid; i < 64 * 64; i += 256) {
        int nl = i >> 6, k = i & 63;
        int n = n0 + nl;
        xs[k][nl] = (n < N) ? x[(size_t)n * 64 + k] : 0.f;
    }
    __syncthreads();

    const int ti = tid & 15, tj = tid >> 4;
    float acc[4][8];
#pragma unroll
    for (int i = 0; i < 4; ++i)
#pragma unroll
        for (int j = 0; j < 8; ++j) acc[i][j] = 0.f;

#pragma unroll 4
    for (int k = 0; k < 64; ++k) {
        const float4 xv = *(const float4*)&xs[k][ti * 4];
        const float4 w0 = *(const float4*)&w2[k][tj * 8];
        const float4 w1 = *(const float4*)&w2[k][tj * 8 + 4];
        const float xa[4] = {xv.x, xv.y, xv.z, xv.w};
        const float wa[8] = {w0.x, w0.y, w0.z, w0.w, w1.x, w1.y, w1.z, w1.w};
#pragma unroll
        for (int i = 0; i < 4; ++i)
#pragma unroll
            for (int j = 0; j < 8; ++j)
                acc[i][j] = fmaf(xa[i], wa[j], acc[i][j]);
    }

#pragma unroll
    for (int i = 0; i < 4; ++i) {
        const int n = n0 + ti * 4 + i;
        if (n < N) {
            if (tj < 8) {
#pragma unroll
                for (int j = 0; j < 8; ++j)
                    A16[(size_t)n * 64 + tj * 8 + j] = __float2bfloat16(acc[i][j]);
            } else {
#pragma unroll
                for (int j = 0; j < 8; ++j) {
                    int d2 = (tj - 8) * 8 + j;
                    B[(size_t)n * 64 + d2] = acc[i][j] + bfs[d2];
                }
            }
        }
    }

    if (tid < 64) {
        const int n = n0 + tid;
        if (n < N) {
            float sc = 0.f, sd = 0.f;
            for (int k = 0; k < 64; ++k) {
                const float xv = xs[k][tid];
                sc = fmaf(xv, ww[k], sc);
                sd = fmaf(xv, ww[64 + k], sd);
            }
            cg[n] = sc;
            dg[n] = sd + bw[0];
        }
    }
}

// Per-block exclusive scan (in -> out, may alias); block totals -> bsum.
// The LAST block to finish (device ticket) then exclusive-scans bsum in place,
// replacing the former scan2 dispatch.
__global__ __launch_bounds__(256) void gat_scan1(
    const int* __restrict__ in, int* __restrict__ out,
    int* __restrict__ bsum, int* __restrict__ ticket, int n, int nb)
{
    __shared__ int tmp[256];
    __shared__ int last;
    const int tid = threadIdx.x;
    const int i = blockIdx.x * 256 + tid;
    const int v = (i < n) ? in[i] : 0;
    tmp[tid] = v;
    __syncthreads();
#pragma unroll
    for (int off = 1; off < 256; off <<= 1) {
        const int add = (tid >= off) ? tmp[tid - off] : 0;
        __syncthreads();
        tmp[tid] += add;
        __syncthreads();
    }
    if (i < n) out[i] = tmp[tid] - v;
    if (tid == 255) bsum[blockIdx.x] = tmp[255];
    __syncthreads();

    // last-block detection (release fence before ticket, acquire after)
    if (tid == 0) {
        __threadfence();
        const int t = atomicAdd(ticket, 1);
        last = (t == (int)gridDim.x - 1) ? 1 : 0;
    }
    __syncthreads();
    if (!last) return;
    __threadfence();

    // exclusive scan of bsum[0..nb) in 256-chunks
    int run = 0;
    for (int base = 0; base < nb; base += 256) {
        const int j = base + tid;
        const int bv = (j < nb) ? bsum[j] : 0;
        __syncthreads();
        tmp[tid] = bv;
        __syncthreads();
#pragma unroll
        for (int off = 1; off < 256; off <<= 1) {
            const int add = (tid >= off) ? tmp[tid - off] : 0;
            __syncthreads();
            tmp[tid] += add;
            __syncthreads();
        }
        if (j < nb) bsum[j] = run + tmp[tid] - bv;   // exclusive
        run += tmp[255];
        __syncthreads();
    }
}

// Partition edges into tgt-buckets; psum = counts[i] + bsum[i>>8] (scan3 folded).
// Packed pair: (src << 8) | (tgt & 255). LDS cursors only. int4 edge reads.
__global__ __launch_bounds__(256) void gat_partition(
    const int* __restrict__ src, const int* __restrict__ tgt,
    const int* __restrict__ counts, const int* __restrict__ bsum,
    unsigned int* __restrict__ pairs, int E, int NB, int chunk)
{
    __shared__ int cur[256];
    const int k = blockIdx.x;
    const int tid = threadIdx.x;
    if (tid < NB) {
        const int idx = tid * NBLK + k;
        cur[tid] = counts[idx] + bsum[idx >> 8];
    }
    __syncthreads();
    const int lo = k * chunk;                // chunk % 4 == 0 -> 16B aligned
    const int hi = min(lo + chunk, E);
    const int m4 = (hi - lo) & ~3;
    for (int e = lo + tid * 4; e < lo + m4; e += 256 * 4) {
        const int4 t4 = *(const int4*)&tgt[e];
        const int4 s4 = *(const int4*)&src[e];
        int p;
        p = atomicAdd(&cur[t4.x >> 8], 1);
        pairs[p] = ((unsigned int)s4.x << 8) | (unsigned int)(t4.x & 255);
        p = atomicAdd(&cur[t4.y >> 8], 1);
        pairs[p] = ((unsigned int)s4.y << 8) | (unsigned int)(t4.y & 255);
        p = atomicAdd(&cur[t4.z >> 8], 1);
        pairs[p] = ((unsigned int)s4.z << 8) | (unsigned int)(t4.z & 255);
        p = atomicAdd(&cur[t4.w >> 8], 1);
        pairs[p] = ((unsigned int)s4.w << 8) | (unsigned int)(t4.w & 255);
    }
    for (int e = lo + m4 + tid; e < hi; e += 256) {
        const int t = tgt[e];
        const int s = src[e];
        const int pos = atomicAdd(&cur[t >> 8], 1);   // LDS atomic (tail)
        pairs[pos] = ((unsigned int)s << 8) | (unsigned int)(t & 255);
    }
}

// Per-bucket counting sort (512 threads): block = bucket of 256 tgt values.
// Emits starts[] (global CSR offsets) and sorted_src[] (contiguous window).
__global__ __launch_bounds__(512) void gat_bucket_sort(
    const unsigned int* __restrict__ pairs, const int* __restrict__ counts,
    const int* __restrict__ bsum,
    int* __restrict__ starts, int* __restrict__ sorted_src,
    int N, int E, int NB)
{
    __shared__ int h[256];
    __shared__ int cur[256];
    const int b = blockIdx.x;
    const int tid = threadIdx.x;
    const int i0 = b * NBLK;
    const int base = counts[i0] + bsum[i0 >> 8];
    int end = E;
    if (b + 1 < NB) {
        const int i1 = (b + 1) * NBLK;
        end = counts[i1] + bsum[i1 >> 8];
    }

    if (tid < 256) h[tid] = 0;
    __syncthreads();
    for (int e = base + tid; e < end; e += 512)
        atomicAdd(&h[pairs[e] & 255u], 1);            // LDS atomic
    __syncthreads();
    const int v = (tid < 256) ? h[tid] : 0;
#pragma unroll
    for (int off = 1; off < 256; off <<= 1) {
        int add = 0;
        if (tid < 256 && tid >= off) add = h[tid - off];
        __syncthreads();
        if (tid < 256) h[tid] += add;
        __syncthreads();
    }
    if (tid < 256) {
        const int excl = h[tid] - v;                  // exclusive within bucket
        const int node = (b << 8) + tid;
        if (node < N) starts[node] = base + excl;
        if (b == NB - 1 && tid == 0) starts[N] = E;
        cur[tid] = base + excl;
    }
    __syncthreads();
    for (int e = base + tid; e < end; e += 512) {
        const unsigned int p = pairs[e];
        const int pos = atomicAdd(&cur[p & 255u], 1); // LDS atomic
        sorted_src[pos] = (int)(p >> 8);
    }
}

__global__ __launch_bounds__(256) void gat_gather(
    const int* __restrict__ starts, const int* __restrict__ sorted_src,
    const __hip_bfloat16* __restrict__ A16, const float* __restrict__ B,
    const float* __restrict__ cg, const float* __restrict__ dg,
    float* __restrict__ out, int N)
{
    const int d = threadIdx.x & 63;
    const int node = blockIdx.x * (blockDim.x >> 6) + (threadIdx.x >> 6);
    if (node >= N) return;
    const int e0 = starts[node];
    const int e1 = starts[node + 1];
    const float Bt  = B[(size_t)node * 64 + d];
    const float dgt = dg[node];
    float acc = 0.f, asum = 0.f;

    int e = e0;
    // unroll x8: 8 independent gather chains in flight per wave
    for (; e + 7 < e1; e += 8) {
        int s[8];
#pragma unroll
        for (int u = 0; u < 8; ++u) s[u] = sorted_src[e + u];
        float a[8], xv[8];
#pragma unroll
        for (int u = 0; u < 8; ++u) a[u] = cg[s[u]] + dgt;
#pragma unroll
        for (int u = 0; u < 8; ++u)
            xv[u] = __bfloat162float(A16[(size_t)s[u] * 64 + d]);
#pragma unroll
        for (int u = 0; u < 8; ++u) {
            acc = fmaf(fmaxf(xv[u] + Bt, 0.f), a[u], acc);
            asum += a[u];
        }
    }
    for (; e + 3 < e1; e += 4) {
        const int s0 = sorted_src[e];
        const int s1 = sorted_src[e + 1];
        const int s2 = sorted_src[e + 2];
        const int s3 = sorted_src[e + 3];
        const float a0 = cg[s0] + dgt;
        const float a1 = cg[s1] + dgt;
        const float a2 = cg[s2] + dgt;
        const float a3 = cg[s3] + dgt;
        const float x0 = __bfloat162float(A16[(size_t)s0 * 64 + d]);
        const float x1 = __bfloat162float(A16[(size_t)s1 * 64 + d]);
        const float x2 = __bfloat162float(A16[(size_t)s2 * 64 + d]);
        const float x3 = __bfloat162float(A16[(size_t)s3 * 64 + d]);
        acc = fmaf(fmaxf(x0 + Bt, 0.f), a0, acc);
        acc = fmaf(fmaxf(x1 + Bt, 0.f), a1, acc);
        acc = fmaf(fmaxf(x2 + Bt, 0.f), a2, acc);
        acc = fmaf(fmaxf(x3 + Bt, 0.f), a3, acc);
        asum += (a0 + a1) + (a2 + a3);
    }
    for (; e < e1; ++e) {
        const int s   = sorted_src[e];
        const float a = cg[s] + dgt;
        const float xv = __bfloat162float(A16[(size_t)s * 64 + d]);
        acc = fmaf(fmaxf(xv + Bt, 0.f), a, acc);
        asum += a;
    }
    out[(size_t)node * 64 + d] = acc / (asum + 1e-6f);
}

extern "C" void kernel_launch(void* const* d_in, const int* in_sizes, int n_in,
                              void* d_out, int out_size, void* d_ws, size_t ws_size,
                              hipStream_t stream)
{
    // setup_inputs order: x, adj, src, tgt, Msrc, Wf, bf, Ww, bw
    const float* x   = (const float*)d_in[0];
    const int*   src = (const int*)d_in[2];
    const int*   tgt = (const int*)d_in[3];
    const float* Wf  = (const float*)d_in[5];
    const float* bf  = (const float*)d_in[6];
    const float* Ww  = (const float*)d_in[7];
    const float* bw  = (const float*)d_in[8];

    const int N = in_sizes[0] / 64;
    const int E = in_sizes[2];
    float* out = (float*)d_out;

    const int NB    = (N + 255) >> 8;                     // 196 buckets
    const int chunk = (((E + NBLK - 1) / NBLK) + 3) & ~3; // mult of 4 (16B-aligned)
    const int NBNB  = NB * NBLK;                          // 100352 counts

    // packed pairs (E u32 = 3.2 MB) live in d_out (12.8 MB): fully consumed by
    // gat_bucket_sort before gat_gather writes out. Stream order guarantees it.
    unsigned int* pairs = (unsigned int*)d_out;

    __hip_bfloat16* A16 = (__hip_bfloat16*)d_ws;          // N*64 bf16 (6.4 MB)
    float* B          = (float*)(A16 + (size_t)N * 64);   // N*64 f32  (12.8 MB)
    float* cg         = B + (size_t)N * 64;               // N
    float* dg         = cg + N;                           // N
    int*   starts     = (int*)(dg + N);                   // N+1
    int*   sorted_src = starts + N + 1;                   // E
    int*   counts     = sorted_src + E;                   // NBNB (401 KB)
    int*   bsum       = counts + NBNB;                    // <=1024
    int*   ticket     = bsum + 1024;                      // 1
    // total ws: ~23.1 MB (<= proven 23.3 MB budget)

    const int nb1 = (N + 63) / 64;
    gat_pre_hist<<<nb1 + NBLK, 256, 0, stream>>>(x, Wf, Ww, bf, bw, A16, B, cg, dg, N,
                                                 tgt, counts, ticket, E, NB, chunk, nb1);
    const int nbs = (NBNB + 255) / 256;   // 392
    gat_scan1<<<nbs, 256, 0, stream>>>(counts, counts, bsum, ticket, NBNB, nbs);
    gat_partition<<<NBLK, 256, 0, stream>>>(src, tgt, counts, bsum, pairs, E, NB, chunk);
    gat_bucket_sort<<<NB, 512, 0, stream>>>(pairs, counts, bsum, starts, sorted_src, N, E, NB);
    const int nb2 = (N + 3) / 4;  // 4 waves (nodes) per 256-thread block
    gat_gather<<<nb2, 256, 0, stream>>>(starts, sorted_src, A16, B, cg, dg, out, N);
}

// Round 14
// 85.421 us; speedup vs baseline: 1.0700x; 1.0700x over previous
//
#include <hip/hip_runtime.h>
#include <hip/hip_bf16.h>

// GAT edge-average forward, factored + CSR via atomic-free bucketed counting sort:
//   A = x @ Wf[:, :64]^T            [N,64]  bf16 in ws
//   B = x @ Wf[:, 64:]^T + bf       [N,64]  f32 in ws
//   c = x @ Ww[0, :64]              [N]
//   d = x @ Ww[0, 64:] + bw         [N]
//   CSR build (no global atomics):
//     hist:   counts[bucket][blk] via LDS histogram (bucket = tgt>>8, NB=196)
//     scan:   2-phase exclusive scan (block offsets folded into consumers)
//     part:   packed (src<<8 | tgt&255) scattered to bucket regions (in d_out)
//     bsort:  per-bucket LDS counting sort, pairs STAGED IN LDS (single global
//             read) -> starts[], sorted_src[]
//   gather: wave=node, lane=dim, unroll x8: acc += relu(A[s]+B[t])*(c[s]+d[t])
// R13 = R11 (best, 86.6us) + LDS-staged bucket_sort. R12's scan-fold reverted.

#define NBLK 512    // edge-chunk blocks for hist/partition
#define PCAP 5376   // LDS stage capacity per bucket (mean 4096, sigma ~64)

__global__ __launch_bounds__(256) void gat_pre_hist(
    const float* __restrict__ x, const float* __restrict__ Wf,
    const float* __restrict__ Ww, const float* __restrict__ bf,
    const float* __restrict__ bw,
    __hip_bfloat16* __restrict__ A16, float* __restrict__ B,
    float* __restrict__ cg, float* __restrict__ dg, int N,
    const int* __restrict__ tgt, int* __restrict__ counts,
    int E, int NB, int chunk, int nb1)
{
    __shared__ float w2[64][132];
    __shared__ float xs[64][68];
    __shared__ float ww[128];
    __shared__ float bfs[64];
    __shared__ int   h[256];

    const int tid = threadIdx.x;

    if (blockIdx.x >= nb1) {
        // LDS-histogram of tgt buckets for this edge chunk; plain global writes
        const int k = blockIdx.x - nb1;          // 0..NBLK-1
        h[tid] = 0;
        __syncthreads();
        const int lo = k * chunk;                // chunk % 4 == 0 -> 16B aligned
        const int hi = min(lo + chunk, E);
        const int m4 = (hi - lo) & ~3;
        for (int e = lo + tid * 4; e < lo + m4; e += 256 * 4) {
            const int4 t4 = *(const int4*)&tgt[e];
            atomicAdd(&h[t4.x >> 8], 1);
            atomicAdd(&h[t4.y >> 8], 1);
            atomicAdd(&h[t4.z >> 8], 1);
            atomicAdd(&h[t4.w >> 8], 1);
        }
        for (int e = lo + m4 + tid; e < hi; e += 256)
            atomicAdd(&h[tgt[e] >> 8], 1);       // LDS atomic (tail)
        __syncthreads();
        if (tid < NB) counts[tid * NBLK + k] = h[tid];
        return;
    }

    for (int f = tid; f < 64 * 128; f += 256) {
        int d  = f >> 7;
        int kk = f & 127;
        w2[kk & 63][(kk >> 6) * 64 + d] = Wf[f];
    }
    if (tid < 128) ww[tid] = Ww[tid];
    if (tid < 64)  bfs[tid] = bf[tid];

    const int n0 = blockIdx.x << 6;
    for (int i = tid; i < 64 * 64; i += 256) {
        int nl = i >> 6, k = i & 63;
        int n = n0 + nl;
        xs[k][nl] = (n < N) ? x[(size_t)n * 64 + k] : 0.f;
    }
    __syncthreads();

    const int ti = tid & 15, tj = tid >> 4;
    float acc[4][8];
#pragma unroll
    for (int i = 0; i < 4; ++i)
#pragma unroll
        for (int j = 0; j < 8; ++j) acc[i][j] = 0.f;

#pragma unroll 4
    for (int k = 0; k < 64; ++k) {
        const float4 xv = *(const float4*)&xs[k][ti * 4];
        const float4 w0 = *(const float4*)&w2[k][tj * 8];
        const float4 w1 = *(const float4*)&w2[k][tj * 8 + 4];
        const float xa[4] = {xv.x, xv.y, xv.z, xv.w};
        const float wa[8] = {w0.x, w0.y, w0.z, w0.w, w1.x, w1.y, w1.z, w1.w};
#pragma unroll
        for (int i = 0; i < 4; ++i)
#pragma unroll
            for (int j = 0; j < 8; ++j)
                acc[i][j] = fmaf(xa[i], wa[j], acc[i][j]);
    }

#pragma unroll
    for (int i = 0; i < 4; ++i) {
        const int n = n0 + ti * 4 + i;
        if (n < N) {
            if (tj < 8) {
#pragma unroll
                for (int j = 0; j < 8; ++j)
                    A16[(size_t)n * 64 + tj * 8 + j] = __float2bfloat16(acc[i][j]);
            } else {
#pragma unroll
                for (int j = 0; j < 8; ++j) {
                    int d2 = (tj - 8) * 8 + j;
                    B[(size_t)n * 64 + d2] = acc[i][j] + bfs[d2];
                }
            }
        }
    }

    if (tid < 64) {
        const int n = n0 + tid;
        if (n < N) {
            float sc = 0.f, sd = 0.f;
            for (int k = 0; k < 64; ++k) {
                const float xv = xs[k][tid];
                sc = fmaf(xv, ww[k], sc);
                sd = fmaf(xv, ww[64 + k], sd);
            }
            cg[n] = sc;
            dg[n] = sd + bw[0];
        }
    }
}

// Phase 1: per-block exclusive scan (in -> out, may alias), block total -> bsum
__global__ __launch_bounds__(256) void gat_scan1(
    const int* __restrict__ in, int* __restrict__ out,
    int* __restrict__ bsum, int n)
{
    __shared__ int tmp[256];
    const int i = blockIdx.x * 256 + threadIdx.x;
    const int v = (i < n) ? in[i] : 0;
    tmp[threadIdx.x] = v;
    __syncthreads();
#pragma unroll
    for (int off = 1; off < 256; off <<= 1) {
        const int add = (threadIdx.x >= off) ? tmp[threadIdx.x - off] : 0;
        __syncthreads();
        tmp[threadIdx.x] += add;
        __syncthreads();
    }
    if (i < n) out[i] = tmp[threadIdx.x] - v;
    if (threadIdx.x == 255) bsum[blockIdx.x] = tmp[255];
}

// Phase 2: single-block exclusive scan of the <=1024 block sums, in place
__global__ __launch_bounds__(1024) void gat_scan2(int* __restrict__ bsum, int nb)
{
    __shared__ int tmp[1024];
    const int v = (threadIdx.x < nb) ? bsum[threadIdx.x] : 0;
    tmp[threadIdx.x] = v;
    __syncthreads();
#pragma unroll
    for (int off = 1; off < 1024; off <<= 1) {
        const int add = (threadIdx.x >= off) ? tmp[threadIdx.x - off] : 0;
        __syncthreads();
        tmp[threadIdx.x] += add;
        __syncthreads();
    }
    if (threadIdx.x < nb) bsum[threadIdx.x] = tmp[threadIdx.x] - v;
}

// Partition edges into tgt-buckets; psum = counts[i] + bsum[i>>8] (scan3 folded).
// Packed pair: (src << 8) | (tgt & 255). LDS cursors only. int4 edge reads.
__global__ __launch_bounds__(256) void gat_partition(
    const int* __restrict__ src, const int* __restrict__ tgt,
    const int* __restrict__ counts, const int* __restrict__ bsum,
    unsigned int* __restrict__ pairs, int E, int NB, int chunk)
{
    __shared__ int cur[256];
    const int k = blockIdx.x;
    const int tid = threadIdx.x;
    if (tid < NB) {
        const int idx = tid * NBLK + k;
        cur[tid] = counts[idx] + bsum[idx >> 8];
    }
    __syncthreads();
    const int lo = k * chunk;                // chunk % 4 == 0 -> 16B aligned
    const int hi = min(lo + chunk, E);
    const int m4 = (hi - lo) & ~3;
    for (int e = lo + tid * 4; e < lo + m4; e += 256 * 4) {
        const int4 t4 = *(const int4*)&tgt[e];
        const int4 s4 = *(const int4*)&src[e];
        int p;
        p = atomicAdd(&cur[t4.x >> 8], 1);
        pairs[p] = ((unsigned int)s4.x << 8) | (unsigned int)(t4.x & 255);
        p = atomicAdd(&cur[t4.y >> 8], 1);
        pairs[p] = ((unsigned int)s4.y << 8) | (unsigned int)(t4.y & 255);
        p = atomicAdd(&cur[t4.z >> 8], 1);
        pairs[p] = ((unsigned int)s4.z << 8) | (unsigned int)(t4.z & 255);
        p = atomicAdd(&cur[t4.w >> 8], 1);
        pairs[p] = ((unsigned int)s4.w << 8) | (unsigned int)(t4.w & 255);
    }
    for (int e = lo + m4 + tid; e < hi; e += 256) {
        const int t = tgt[e];
        const int s = src[e];
        const int pos = atomicAdd(&cur[t >> 8], 1);   // LDS atomic (tail)
        pairs[pos] = ((unsigned int)s << 8) | (unsigned int)(t & 255);
    }
}

// Per-bucket counting sort: block = bucket of 256 consecutive tgt values.
// Pairs staged in LDS (one global read); emits starts[] and sorted_src[].
__global__ __launch_bounds__(256) void gat_bucket_sort(
    const unsigned int* __restrict__ pairs, const int* __restrict__ counts,
    const int* __restrict__ bsum,
    int* __restrict__ starts, int* __restrict__ sorted_src,
    int N, int E, int NB)
{
    __shared__ int h[256];
    __shared__ int cur[256];
    __shared__ unsigned int plds[PCAP];
    const int b = blockIdx.x;
    const int tid = threadIdx.x;
    const int i0 = b * NBLK;
    const int base = counts[i0] + bsum[i0 >> 8];
    int end = E;
    if (b + 1 < NB) {
        const int i1 = (b + 1) * NBLK;
        end = counts[i1] + bsum[i1 >> 8];
    }
    const int cnt = end - base;
    const bool fits = (cnt <= PCAP);

    h[tid] = 0;
    if (fits) {
        for (int e = tid; e < cnt; e += 256) plds[e] = pairs[base + e];
    }
    __syncthreads();

    if (fits) {
        for (int e = tid; e < cnt; e += 256)
            atomicAdd(&h[plds[e] & 255u], 1);         // LDS atomic
    } else {
        for (int e = base + tid; e < end; e += 256)
            atomicAdd(&h[pairs[e] & 255u], 1);
    }
    __syncthreads();
    const int v = h[tid];
#pragma unroll
    for (int off = 1; off < 256; off <<= 1) {
        const int add = (tid >= off) ? h[tid - off] : 0;
        __syncthreads();
        h[tid] += add;
        __syncthreads();
    }
    const int excl = h[tid] - v;                      // exclusive within bucket
    const int node = (b << 8) + tid;
    if (node < N) starts[node] = base + excl;
    if (b == NB - 1 && tid == 0) starts[N] = E;
    cur[tid] = base + excl;
    __syncthreads();
    if (fits) {
        for (int e = tid; e < cnt; e += 256) {
            const unsigned int p = plds[e];
            const int pos = atomicAdd(&cur[p & 255u], 1);  // LDS atomic
            sorted_src[pos] = (int)(p >> 8);
        }
    } else {
        for (int e = base + tid; e < end; e += 256) {
            const unsigned int p = pairs[e];
            const int pos = atomicAdd(&cur[p & 255u], 1);
            sorted_src[pos] = (int)(p >> 8);
        }
    }
}

__global__ __launch_bounds__(256) void gat_gather(
    const int* __restrict__ starts, const int* __restrict__ sorted_src,
    const __hip_bfloat16* __restrict__ A16, const float* __restrict__ B,
    const float* __restrict__ cg, const float* __restrict__ dg,
    float* __restrict__ out, int N)
{
    const int d = threadIdx.x & 63;
    const int node = blockIdx.x * (blockDim.x >> 6) + (threadIdx.x >> 6);
    if (node >= N) return;
    const int e0 = starts[node];
    const int e1 = starts[node + 1];
    const float Bt  = B[(size_t)node * 64 + d];
    const float dgt = dg[node];
    float acc = 0.f, asum = 0.f;

    int e = e0;
    // unroll x8: 8 independent gather chains in flight per wave
    for (; e + 7 < e1; e += 8) {
        int s[8];
#pragma unroll
        for (int u = 0; u < 8; ++u) s[u] = sorted_src[e + u];
        float a[8], xv[8];
#pragma unroll
        for (int u = 0; u < 8; ++u) a[u] = cg[s[u]] + dgt;
#pragma unroll
        for (int u = 0; u < 8; ++u)
            xv[u] = __bfloat162float(A16[(size_t)s[u] * 64 + d]);
#pragma unroll
        for (int u = 0; u < 8; ++u) {
            acc = fmaf(fmaxf(xv[u] + Bt, 0.f), a[u], acc);
            asum += a[u];
        }
    }
    for (; e + 3 < e1; e += 4) {
        const int s0 = sorted_src[e];
        const int s1 = sorted_src[e + 1];
        const int s2 = sorted_src[e + 2];
        const int s3 = sorted_src[e + 3];
        const float a0 = cg[s0] + dgt;
        const float a1 = cg[s1] + dgt;
        const float a2 = cg[s2] + dgt;
        const float a3 = cg[s3] + dgt;
        const float x0 = __bfloat162float(A16[(size_t)s0 * 64 + d]);
        const float x1 = __bfloat162float(A16[(size_t)s1 * 64 + d]);
        const float x2 = __bfloat162float(A16[(size_t)s2 * 64 + d]);
        const float x3 = __bfloat162float(A16[(size_t)s3 * 64 + d]);
        acc = fmaf(fmaxf(x0 + Bt, 0.f), a0, acc);
        acc = fmaf(fmaxf(x1 + Bt, 0.f), a1, acc);
        acc = fmaf(fmaxf(x2 + Bt, 0.f), a2, acc);
        acc = fmaf(fmaxf(x3 + Bt, 0.f), a3, acc);
        asum += (a0 + a1) + (a2 + a3);
    }
    for (; e < e1; ++e) {
        const int s   = sorted_src[e];
        const float a = cg[s] + dgt;
        const float xv = __bfloat162float(A16[(size_t)s * 64 + d]);
        acc = fmaf(fmaxf(xv + Bt, 0.f), a, acc);
        asum += a;
    }
    out[(size_t)node * 64 + d] = acc / (asum + 1e-6f);
}

extern "C" void kernel_launch(void* const* d_in, const int* in_sizes, int n_in,
                              void* d_out, int out_size, void* d_ws, size_t ws_size,
                              hipStream_t stream)
{
    // setup_inputs order: x, adj, src, tgt, Msrc, Wf, bf, Ww, bw
    const float* x   = (const float*)d_in[0];
    const int*   src = (const int*)d_in[2];
    const int*   tgt = (const int*)d_in[3];
    const float* Wf  = (const float*)d_in[5];
    const float* bf  = (const float*)d_in[6];
    const float* Ww  = (const float*)d_in[7];
    const float* bw  = (const float*)d_in[8];

    const int N = in_sizes[0] / 64;
    const int E = in_sizes[2];
    float* out = (float*)d_out;

    const int NB    = (N + 255) >> 8;                     // 196 buckets
    const int chunk = (((E + NBLK - 1) / NBLK) + 3) & ~3; // mult of 4 (16B-aligned)
    const int NBNB  = NB * NBLK;                          // 100352 counts

    // packed pairs (E u32 = 3.2 MB) live in d_out (12.8 MB): fully consumed by
    // gat_bucket_sort before gat_gather writes out. Stream order guarantees it.
    unsigned int* pairs = (unsigned int*)d_out;

    __hip_bfloat16* A16 = (__hip_bfloat16*)d_ws;          // N*64 bf16 (6.4 MB)
    float* B          = (float*)(A16 + (size_t)N * 64);   // N*64 f32  (12.8 MB)
    float* cg         = B + (size_t)N * 64;               // N
    float* dg         = cg + N;                           // N
    int*   starts     = (int*)(dg + N);                   // N+1
    int*   sorted_src = starts + N + 1;                   // E
    int*   counts     = sorted_src + E;                   // NBNB (401 KB)
    int*   bsum       = counts + NBNB;                    // <=1024
    // total ws: ~23.1 MB (<= proven 23.3 MB budget)

    const int nb1 = (N + 63) / 64;
    gat_pre_hist<<<nb1 + NBLK, 256, 0, stream>>>(x, Wf, Ww, bf, bw, A16, B, cg, dg, N,
                                                 tgt, counts, E, NB, chunk, nb1);
    const int nbs = (NBNB + 255) / 256;   // 392 <= 1024
    gat_scan1<<<nbs, 256, 0, stream>>>(counts, counts, bsum, NBNB);
    gat_scan2<<<1, 1024, 0, stream>>>(bsum, nbs);
    gat_partition<<<NBLK, 256, 0, stream>>>(src, tgt, counts, bsum, pairs, E, NB, chunk);
    gat_bucket_sort<<<NB, 256, 0, stream>>>(pairs, counts, bsum, starts, sorted_src, N, E, NB);
    const int nb2 = (N + 3) / 4;  // 4 waves (nodes) per 256-thread block
    gat_gather<<<nb2, 256, 0, stream>>>(starts, sorted_src, A16, B, cg, dg, out, N);
}